// Round 4
// baseline (3105.586 us; speedup 1.0000x reference)
//
#include <hip/hip_runtime.h>
#include <math.h>

#define KNN 20
#define NPTS 4096
#define NB 8

__device__ __forceinline__ bool lexless(float d1, int i1, float d2, int i2) {
    return d1 < d2 || (d1 == d2 && i1 < i2);
}

// ---------------------------------------------------------------- concat x|pos
__global__ __launch_bounds__(256) void concat_kernel(const float* __restrict__ x,
                                                     const float* __restrict__ pos,
                                                     float* __restrict__ f0, int total) {
    int p = blockIdx.x * 256 + threadIdx.x;
    if (p < total) {
        f0[(size_t)p*6 + 0] = x[(size_t)p*3 + 0];
        f0[(size_t)p*6 + 1] = x[(size_t)p*3 + 1];
        f0[(size_t)p*6 + 2] = x[(size_t)p*3 + 2];
        f0[(size_t)p*6 + 3] = pos[(size_t)p*3 + 0];
        f0[(size_t)p*6 + 4] = pos[(size_t)p*3 + 1];
        f0[(size_t)p*6 + 5] = pos[(size_t)p*3 + 2];
    }
}

// ---------------------------------------------------------------- squared norms
template<int C>
__global__ __launch_bounds__(256) void norm_kernel(const float* __restrict__ f, int ldf,
                                                   float* __restrict__ norms, int total) {
    int p = blockIdx.x * 256 + threadIdx.x;
    if (p >= total) return;
    const float* fp = f + (size_t)p * ldf;
    float s = 0.f;
    if constexpr ((C & 3) == 0) {
#pragma unroll
        for (int k = 0; k < C; k += 4) {
            float4 v = *(const float4*)(fp + k);
            s = fmaf(v.x, v.x, s); s = fmaf(v.y, v.y, s);
            s = fmaf(v.z, v.z, s); s = fmaf(v.w, v.w, s);
        }
    } else {
#pragma unroll
        for (int k = 0; k < C; ++k) s = fmaf(fp[k], fp[k], s);
    }
    norms[p] = s;
}

// ---- sortable-key top-k machinery -------------------------------------------
// key = (sign-fixed float bits << 32) | idx ; u64 '<' == lexless((d,idx)).
// NOTE: internal names (kc, mk) chosen to avoid macro variable capture —
// KCHAIN(mk) must NOT shadow its argument (round-3 bug: KCHAIN's local was
// named 'ck' and KMERGE passed a variable also named 'ck' -> self-init UB).
#define KCHAIN(ck_) do {                                                 \
    unsigned long long kc = (ck_);                                       \
    _Pragma("unroll")                                                    \
    for (int t = 0; t < KNN; ++t) {                                      \
        bool sw = kc < bk[t];                                            \
        unsigned long long nn = sw ? kc : bk[t];                         \
        unsigned long long oo = sw ? bk[t] : kc;                         \
        bk[t] = nn; kc = oo;                                             \
    }                                                                    \
} while (0)

#define KFLUSH() do {                                                    \
    if (cnt > 0) KCHAIN(e0);                                             \
    if (cnt > 1) KCHAIN(e1);                                             \
    if (cnt > 2) KCHAIN(e2);                                             \
    if (cnt > 3) KCHAIN(e3);                                             \
    cnt = 0;                                                             \
} while (0)

#define KPUSH(dv_, jg_) do {                                             \
    unsigned u = __float_as_uint(dv_);                                   \
    u = (u == 0x80000000u) ? 0u : u;        /* -0 -> +0 */               \
    u ^= (unsigned)((int)u >> 31) | 0x80000000u;                         \
    unsigned long long pk = ((unsigned long long)u << 32) | (unsigned)(jg_); \
    if (pk < bk[KNN - 1]) {                                              \
        e3 = e2; e2 = e1; e1 = e0; e0 = pk; ++cnt;                       \
    }                                                                    \
} while (0)

#define KMERGE(ptr_) do {                                                \
    const unsigned long long* mp = (ptr_);                               \
    _Pragma("unroll 1")                                                  \
    for (int tm = 0; tm < KNN; ++tm) {                                   \
        unsigned long long mk = mp[tm];                                  \
        if (mk >= bk[KNN - 1]) break;                                    \
        KCHAIN(mk);                                                      \
    }                                                                    \
} while (0)

// ---------------------------------------------------------------- fused tiled kNN
// 512-thread block handles 64 queries. Wave w (of 8) scans candidate sub-range
// [8w,8w+8) of every 64-candidate tile (lane = query). GEMM: 2x4 micro-tiles.
// Distances computed in GEMM epilogue (d = qn + cn - 2*dot) into Ds.
// End: 3-round hierarchical in-block merge of the 8 sorted 20-lists per query.
template<int C>
__global__ __launch_bounds__(512, 4) void knn_tile_kernel(const float* __restrict__ f, int ldf,
                                                          const float* __restrict__ norms,
                                                          int* __restrict__ idx) {
    const int qb    = blockIdx.x * 64;      // global query base
    const int b     = qb >> 12;             // batch
    const int qloc0 = qb & (NPTS - 1);
    const int tid   = threadIdx.x;
    const int lane  = tid & 63;             // query within tile (scan/merge role)
    const int wv    = tid >> 6;             // wave id = candidate sub-group 0..7
    const int tx    = tid & 15;             // candidate quad (GEMM role)
    const int ty    = tid >> 4;             // query pair 0..31 (GEMM role)

    union __align__(16) SM {
        struct {
            float Qs[C][64];
            float Cs[C][64];
            float Ds[64][68];               // padded: rows 16B-aligned
        } a;
        unsigned long long md[64][4 * KNN + 1];   // merge lists (padded stride)
    };
    __shared__ SM sm;

    const float* fb = f + (size_t)b * NPTS * ldf;
    const float* nb = norms + (size_t)b * NPTS;

    // ---- stage query tile Qs[k][m]
    if constexpr ((C & 7) == 0) {
        const int k0 = wv * (C / 8);
        const float* src = fb + (size_t)(qloc0 + lane) * ldf + k0;
#pragma unroll
        for (int i = 0; i < C / 8; i += 4) {
            float4 v = *(const float4*)(src + i);
            sm.a.Qs[k0 + i + 0][lane] = v.x;
            sm.a.Qs[k0 + i + 1][lane] = v.y;
            sm.a.Qs[k0 + i + 2][lane] = v.z;
            sm.a.Qs[k0 + i + 3][lane] = v.w;
        }
    } else {
        for (int e = tid; e < C * 64; e += 512) {
            int k = e >> 6, m = e & 63;
            sm.a.Qs[k][m] = fb[(size_t)(qloc0 + m) * ldf + k];
        }
    }

    const float qn0 = nb[qloc0 + ty * 2 + 0];   // norms of this thread's GEMM rows
    const float qn1 = nb[qloc0 + ty * 2 + 1];

    unsigned long long bk[KNN];
#pragma unroll
    for (int t = 0; t < KNN; ++t) bk[t] = ~0ULL;
    unsigned long long e0 = ~0ULL, e1 = ~0ULL, e2 = ~0ULL, e3 = ~0ULL;
    int cnt = 0;

    for (int j0 = 0; j0 < NPTS; j0 += 64) {
        __syncthreads();   // prev scan done before restaging Cs

        // ---- stage candidate tile Cs[k][j]
        if constexpr ((C & 7) == 0) {
            const int k0 = wv * (C / 8);
            const float* src = fb + (size_t)(j0 + lane) * ldf + k0;
#pragma unroll
            for (int i = 0; i < C / 8; i += 4) {
                float4 v = *(const float4*)(src + i);
                sm.a.Cs[k0 + i + 0][lane] = v.x;
                sm.a.Cs[k0 + i + 1][lane] = v.y;
                sm.a.Cs[k0 + i + 2][lane] = v.z;
                sm.a.Cs[k0 + i + 3][lane] = v.w;
            }
        } else {
            for (int e = tid; e < C * 64; e += 512) {
                int k = e >> 6, j = e & 63;
                sm.a.Cs[k][j] = fb[(size_t)(j0 + j) * ldf + k];
            }
        }
        __syncthreads();

        // ---- 64x64xC dot tile, 2x4 micro-tile per thread
        float acc[2][4] = {};
#pragma unroll 8
        for (int kk = 0; kk < C; ++kk) {
            const float2 av = *(const float2*)&sm.a.Qs[kk][ty * 2];
            const float4 bv = *(const float4*)&sm.a.Cs[kk][tx * 4];
            acc[0][0] = fmaf(av.x, bv.x, acc[0][0]);
            acc[0][1] = fmaf(av.x, bv.y, acc[0][1]);
            acc[0][2] = fmaf(av.x, bv.z, acc[0][2]);
            acc[0][3] = fmaf(av.x, bv.w, acc[0][3]);
            acc[1][0] = fmaf(av.y, bv.x, acc[1][0]);
            acc[1][1] = fmaf(av.y, bv.y, acc[1][1]);
            acc[1][2] = fmaf(av.y, bv.z, acc[1][2]);
            acc[1][3] = fmaf(av.y, bv.w, acc[1][3]);
        }
        // ---- epilogue: full squared distances into Ds
        const float4 cnv = *(const float4*)(nb + j0 + tx * 4);
        float4 d0, d1;
        d0.x = fmaf(-2.0f, acc[0][0], qn0 + cnv.x);
        d0.y = fmaf(-2.0f, acc[0][1], qn0 + cnv.y);
        d0.z = fmaf(-2.0f, acc[0][2], qn0 + cnv.z);
        d0.w = fmaf(-2.0f, acc[0][3], qn0 + cnv.w);
        d1.x = fmaf(-2.0f, acc[1][0], qn1 + cnv.x);
        d1.y = fmaf(-2.0f, acc[1][1], qn1 + cnv.y);
        d1.z = fmaf(-2.0f, acc[1][2], qn1 + cnv.z);
        d1.w = fmaf(-2.0f, acc[1][3], qn1 + cnv.w);
        *(float4*)&sm.a.Ds[ty * 2 + 0][tx * 4] = d0;
        *(float4*)&sm.a.Ds[ty * 2 + 1][tx * 4] = d1;
        __syncthreads();

        // ---- scan: wave wv handles candidates [8wv, 8wv+8) for query 'lane'
        const float4 v0 = *(const float4*)&sm.a.Ds[lane][wv * 8 + 0];
        const float4 v1 = *(const float4*)&sm.a.Ds[lane][wv * 8 + 4];
        const int jg = j0 + wv * 8;
        KPUSH(v0.x, jg + 0); KPUSH(v0.y, jg + 1); if (__any(cnt >= 3)) KFLUSH();
        KPUSH(v0.z, jg + 2); KPUSH(v0.w, jg + 3); if (__any(cnt >= 3)) KFLUSH();
        KPUSH(v1.x, jg + 4); KPUSH(v1.y, jg + 5); if (__any(cnt >= 3)) KFLUSH();
        KPUSH(v1.z, jg + 6); KPUSH(v1.w, jg + 7); if (__any(cnt >= 3)) KFLUSH();
    }
    if (__any(cnt > 0)) KFLUSH();

    // ---- hierarchical 8 -> 1 merge of sorted lists (per query = per lane)
    __syncthreads();   // all Ds reads done; alias md over a.*

    if (wv >= 4) {
#pragma unroll
        for (int t = 0; t < KNN; ++t) sm.md[lane][(wv - 4) * KNN + t] = bk[t];
    }
    __syncthreads();
    if (wv < 4) KMERGE(&sm.md[lane][wv * KNN]);
    __syncthreads();
    if (wv == 2 || wv == 3) {
#pragma unroll
        for (int t = 0; t < KNN; ++t) sm.md[lane][(wv - 2) * KNN + t] = bk[t];
    }
    __syncthreads();
    if (wv < 2) KMERGE(&sm.md[lane][wv * KNN]);
    __syncthreads();
    if (wv == 1) {
#pragma unroll
        for (int t = 0; t < KNN; ++t) sm.md[lane][t] = bk[t];
    }
    __syncthreads();
    if (wv == 0) {
        KMERGE(&sm.md[lane][0]);
        int* op = idx + (size_t)(qb + lane) * KNN;
#pragma unroll
        for (int t = 0; t < KNN; ++t) op[t] = (int)bk[t];
    }
}

// ---------------------------------------------------------------- EdgeConv (wave/point)
template<int C>
__global__ __launch_bounds__(64) void edgeconv_kernel(
    const float* __restrict__ f, int ldf,
    const int* __restrict__ idx,
    const float* __restrict__ W1, const float* __restrict__ b1,
    const float* __restrict__ g,  const float* __restrict__ be,
    const float* __restrict__ W2, const float* __restrict__ b2,
    float* __restrict__ out, int ldo) {
    const int p = blockIdx.x;
    const int b = p >> 12;
    const int i = p & (NPTS - 1);
    const int c = threadIdx.x;   // output channel, 0..63
    __shared__ __align__(16) float fi_s[C];
    __shared__ __align__(16) float fj_s[KNN][C];
    __shared__ __align__(16) float h1_s[KNN][64];
    __shared__ int nidx[KNN];
    const float* fb = f + (size_t)b * NPTS * ldf;
    if (c < KNN) nidx[c] = idx[(size_t)p * KNN + c];
    if (c < C)   fi_s[c] = fb[(size_t)i * ldf + c];
    __syncthreads();
#pragma unroll
    for (int j = 0; j < KNN; ++j)
        if (c < C) fj_s[j][c] = fb[(size_t)nidx[j] * ldf + c];
    __syncthreads();
    float fir[C];
#pragma unroll
    for (int k = 0; k < C; ++k) fir[k] = fi_s[k];

    const float bn_s = (float)(1.0 / sqrt(1.0 + 1e-5));
    const float bnscale = g[c] * bn_s;
    float base = b1[c];
#pragma unroll
    for (int k = 0; k < C; ++k) base = fmaf(fir[k], W1[k * 64 + c], base);
    float acc[KNN];
#pragma unroll
    for (int j = 0; j < KNN; ++j) acc[j] = base;

    if constexpr ((C & 3) == 0) {
#pragma unroll
        for (int k = 0; k < C; k += 4) {
            float w0 = W1[(C + k + 0) * 64 + c];
            float w1 = W1[(C + k + 1) * 64 + c];
            float w2 = W1[(C + k + 2) * 64 + c];
            float w3 = W1[(C + k + 3) * 64 + c];
            float f0 = fir[k + 0], f1 = fir[k + 1], f2 = fir[k + 2], f3 = fir[k + 3];
#pragma unroll
            for (int j = 0; j < KNN; ++j) {
                float4 v = *(const float4*)&fj_s[j][k];
                acc[j] = fmaf(v.x - f0, w0, acc[j]);
                acc[j] = fmaf(v.y - f1, w1, acc[j]);
                acc[j] = fmaf(v.z - f2, w2, acc[j]);
                acc[j] = fmaf(v.w - f3, w3, acc[j]);
            }
        }
    } else {
#pragma unroll
        for (int k = 0; k < C; ++k) {
            float w = W1[(C + k) * 64 + c];
            float fik = fir[k];
#pragma unroll
            for (int j = 0; j < KNN; ++j) acc[j] = fmaf(fj_s[j][k] - fik, w, acc[j]);
        }
    }
    float bec = be[c];
#pragma unroll
    for (int j = 0; j < KNN; ++j) h1_s[j][c] = fmaxf(fmaf(acc[j], bnscale, bec), 0.f);
    __syncthreads();

    float acc2[KNN];
    float b2c = b2[c];
#pragma unroll
    for (int j = 0; j < KNN; ++j) acc2[j] = b2c;
#pragma unroll
    for (int k = 0; k < 64; k += 4) {
        float w0 = W2[(k + 0) * 64 + c];
        float w1 = W2[(k + 1) * 64 + c];
        float w2 = W2[(k + 2) * 64 + c];
        float w3 = W2[(k + 3) * 64 + c];
#pragma unroll
        for (int j = 0; j < KNN; ++j) {
            float4 v = *(const float4*)&h1_s[j][k];
            acc2[j] = fmaf(v.x, w0, acc2[j]);
            acc2[j] = fmaf(v.y, w1, acc2[j]);
            acc2[j] = fmaf(v.z, w2, acc2[j]);
            acc2[j] = fmaf(v.w, w3, acc2[j]);
        }
    }
    float m = acc2[0];
#pragma unroll
    for (int j = 1; j < KNN; ++j) m = fmaxf(m, acc2[j]);
    out[(size_t)p * ldo + c] = m;
}

// ---------------------------------------------------------------- tiled fp32 GEMM: C = act(A@W + b)
template<int BM, int BN, int BK, bool RELU>
__global__ __launch_bounds__(256) void gemm_kernel(
    const float* __restrict__ A, int lda,
    const float* __restrict__ W,          // [K, N] row-major
    const float* __restrict__ bias,
    float* __restrict__ Cc, int ldc,
    int N, int K) {
    __shared__ __align__(16) float As[BK][BM];
    __shared__ __align__(16) float Bs[BK][BN];
    const int bm = blockIdx.y * BM;
    const int bn = blockIdx.x * BN;
    const int tid = threadIdx.x;
    const int tx = tid & 15, ty = tid >> 4;
    float acc[4][4] = {};
    for (int k0 = 0; k0 < K; k0 += BK) {
        {   // A tile: 64 rows x 16 cols, each thread float4
            int m = tid >> 2;
            int kq = (tid & 3) * 4;
            float4 v = *(const float4*)(A + (size_t)(bm + m) * lda + k0 + kq);
            As[kq + 0][m] = v.x; As[kq + 1][m] = v.y; As[kq + 2][m] = v.z; As[kq + 3][m] = v.w;
        }
        {   // W tile: 16 rows x 64 cols
            int kk = tid >> 4;
            int n4 = (tid & 15) * 4;
            float4 v = *(const float4*)(W + (size_t)(k0 + kk) * N + bn + n4);
            *(float4*)&Bs[kk][n4] = v;
        }
        __syncthreads();
#pragma unroll
        for (int kk = 0; kk < BK; ++kk) {
            float4 av = *(const float4*)&As[kk][ty * 4];
            float4 bv = *(const float4*)&Bs[kk][tx * 4];
            float a[4] = {av.x, av.y, av.z, av.w};
            float bb[4] = {bv.x, bv.y, bv.z, bv.w};
#pragma unroll
            for (int i = 0; i < 4; ++i)
#pragma unroll
                for (int j = 0; j < 4; ++j) acc[i][j] = fmaf(a[i], bb[j], acc[i][j]);
        }
        __syncthreads();
    }
#pragma unroll
    for (int i = 0; i < 4; ++i) {
        int m = bm + ty * 4 + i;
        float4 o;
        o.x = acc[i][0] + bias[bn + tx * 4 + 0];
        o.y = acc[i][1] + bias[bn + tx * 4 + 1];
        o.z = acc[i][2] + bias[bn + tx * 4 + 2];
        o.w = acc[i][3] + bias[bn + tx * 4 + 3];
        if (RELU) {
            o.x = fmaxf(o.x, 0.f); o.y = fmaxf(o.y, 0.f);
            o.z = fmaxf(o.z, 0.f); o.w = fmaxf(o.w, 0.f);
        }
        *(float4*)(Cc + (size_t)m * ldc + bn + tx * 4) = o;
    }
}

// ---------------------------------------------------------------- final layer (K=128 -> 40) + log_softmax
__global__ __launch_bounds__(64) void head_kernel(const float* __restrict__ h3,
                                                  const float* __restrict__ W4,
                                                  const float* __restrict__ b4,
                                                  float* __restrict__ out) {
    const int p = blockIdx.x;
    const int lane = threadIdx.x;
    const float* hp = h3 + (size_t)p * 128;
    float v = -INFINITY;
    if (lane < 40) {
        float acc = b4[lane];
#pragma unroll
        for (int k = 0; k < 128; ++k) acc = fmaf(hp[k], W4[k * 40 + lane], acc);
        v = acc;
    }
    float mx = v;
#pragma unroll
    for (int s = 1; s < 64; s <<= 1) mx = fmaxf(mx, __shfl_xor(mx, s));
    float e = (lane < 40) ? expf(v - mx) : 0.0f;
    float se = e;
#pragma unroll
    for (int s = 1; s < 64; s <<= 1) se += __shfl_xor(se, s);
    if (lane < 40) out[(size_t)p * 40 + lane] = v - mx - logf(se);
}

// ----------------------------------------------------------------
extern "C" void kernel_launch(void* const* d_in, const int* in_sizes, int n_in,
                              void* d_out, int out_size, void* d_ws, size_t ws_size,
                              hipStream_t stream) {
    (void)in_sizes; (void)n_in; (void)out_size; (void)ws_size;
    const float* x     = (const float*)d_in[0];
    const float* pos   = (const float*)d_in[1];
    const float* c1_W1 = (const float*)d_in[2];
    const float* c1_b1 = (const float*)d_in[3];
    const float* c1_g  = (const float*)d_in[4];
    const float* c1_be = (const float*)d_in[5];
    const float* c1_W2 = (const float*)d_in[6];
    const float* c1_b2 = (const float*)d_in[7];
    const float* c2_W1 = (const float*)d_in[8];
    const float* c2_b1 = (const float*)d_in[9];
    const float* c2_g  = (const float*)d_in[10];
    const float* c2_be = (const float*)d_in[11];
    const float* c2_W2 = (const float*)d_in[12];
    const float* c2_b2 = (const float*)d_in[13];
    const float* c3_W1 = (const float*)d_in[14];
    const float* c3_b1 = (const float*)d_in[15];
    const float* c3_g  = (const float*)d_in[16];
    const float* c3_be = (const float*)d_in[17];
    const float* c3_W2 = (const float*)d_in[18];
    const float* c3_b2 = (const float*)d_in[19];
    const float* m_W1  = (const float*)d_in[20];
    const float* m_b1  = (const float*)d_in[21];
    const float* m_W2  = (const float*)d_in[22];
    const float* m_b2  = (const float*)d_in[23];
    const float* m_W3  = (const float*)d_in[24];
    const float* m_b3  = (const float*)d_in[25];
    const float* m_W4  = (const float*)d_in[26];
    const float* m_b4  = (const float*)d_in[27];
    float* out = (float*)d_out;

    const int TOT = NB * NPTS;  // 32768

    // workspace layout (floats):
    float* ws   = (float*)d_ws;
    float* f0   = ws;                              // 196608
    int*   idxb = (int*)(ws + 196608);             // 655360 ints
    float* feat = ws + 196608 + 655360;            // 6291456  [32768 x 192]
    float* h1   = feat + 6291456;                  // 4194304  [4096 x 1024]
    float* h2   = h1 + 4194304;                    // 1048576  [4096 x 256]
    float* h3   = h2 + 1048576;                    // 524288   [4096 x 128]
    float* nrm  = h1;                              // alias: h1 only used in MLP phase

    concat_kernel<<<(TOT + 255) / 256, 256, 0, stream>>>(x, pos, f0, TOT);

    norm_kernel<6><<<(TOT + 255) / 256, 256, 0, stream>>>(f0, 6, nrm, TOT);
    knn_tile_kernel<6><<<TOT / 64, 512, 0, stream>>>(f0, 6, nrm, idxb);
    edgeconv_kernel<6><<<TOT, 64, 0, stream>>>(f0, 6, idxb,
        c1_W1, c1_b1, c1_g, c1_be, c1_W2, c1_b2, feat + 0, 192);

    norm_kernel<64><<<(TOT + 255) / 256, 256, 0, stream>>>(feat + 0, 192, nrm, TOT);
    knn_tile_kernel<64><<<TOT / 64, 512, 0, stream>>>(feat + 0, 192, nrm, idxb);
    edgeconv_kernel<64><<<TOT, 64, 0, stream>>>(feat + 0, 192, idxb,
        c2_W1, c2_b1, c2_g, c2_be, c2_W2, c2_b2, feat + 64, 192);

    norm_kernel<64><<<(TOT + 255) / 256, 256, 0, stream>>>(feat + 64, 192, nrm, TOT);
    knn_tile_kernel<64><<<TOT / 64, 512, 0, stream>>>(feat + 64, 192, nrm, idxb);
    edgeconv_kernel<64><<<TOT, 64, 0, stream>>>(feat + 64, 192, idxb,
        c3_W1, c3_b1, c3_g, c3_be, c3_W2, c3_b2, feat + 128, 192);

    const int MC = 4096;
    for (int mc = 0; mc < TOT; mc += MC) {
        gemm_kernel<64, 64, 16, true><<<dim3(1024 / 64, MC / 64), 256, 0, stream>>>(
            feat + (size_t)mc * 192, 192, m_W1, m_b1, h1, 1024, 1024, 192);
        gemm_kernel<64, 64, 16, true><<<dim3(256 / 64, MC / 64), 256, 0, stream>>>(
            h1, 1024, m_W2, m_b2, h2, 256, 256, 1024);
        gemm_kernel<64, 64, 16, true><<<dim3(128 / 64, MC / 64), 256, 0, stream>>>(
            h2, 256, m_W3, m_b3, h3, 128, 128, 256);
        head_kernel<<<MC, 64, 0, stream>>>(h3, m_W4, m_b4, out + (size_t)mc * 40);
    }
}

// Round 5
// 2785.041 us; speedup vs baseline: 1.1151x; 1.1151x over previous
//
#include <hip/hip_runtime.h>
#include <math.h>

#define KNN 20
#define NPTS 4096
#define NB 8

__device__ __forceinline__ bool lexless(float d1, int i1, float d2, int i2) {
    return d1 < d2 || (d1 == d2 && i1 < i2);
}

// ---------------------------------------------------------------- concat x|pos
__global__ __launch_bounds__(256) void concat_kernel(const float* __restrict__ x,
                                                     const float* __restrict__ pos,
                                                     float* __restrict__ f0, int total) {
    int p = blockIdx.x * 256 + threadIdx.x;
    if (p < total) {
        f0[(size_t)p*6 + 0] = x[(size_t)p*3 + 0];
        f0[(size_t)p*6 + 1] = x[(size_t)p*3 + 1];
        f0[(size_t)p*6 + 2] = x[(size_t)p*3 + 2];
        f0[(size_t)p*6 + 3] = pos[(size_t)p*3 + 0];
        f0[(size_t)p*6 + 4] = pos[(size_t)p*3 + 1];
        f0[(size_t)p*6 + 5] = pos[(size_t)p*3 + 2];
    }
}

// ---------------------------------------------------------------- squared norms
template<int C>
__global__ __launch_bounds__(256) void norm_kernel(const float* __restrict__ f, int ldf,
                                                   float* __restrict__ norms, int total) {
    int p = blockIdx.x * 256 + threadIdx.x;
    if (p >= total) return;
    const float* fp = f + (size_t)p * ldf;
    float s = 0.f;
    if constexpr ((C & 3) == 0) {
#pragma unroll
        for (int k = 0; k < C; k += 4) {
            float4 v = *(const float4*)(fp + k);
            s = fmaf(v.x, v.x, s); s = fmaf(v.y, v.y, s);
            s = fmaf(v.z, v.z, s); s = fmaf(v.w, v.w, s);
        }
    } else {
#pragma unroll
        for (int k = 0; k < C; ++k) s = fmaf(fp[k], fp[k], s);
    }
    norms[p] = s;
}

// ---- sortable-key top-k machinery -------------------------------------------
// key = (sign-fixed float bits << 32) | idx ; u64 '<' == lexless((d,idx)).
// Internal names chosen to avoid macro variable capture (round-3 lesson).
#define KCHAIN(ck_) do {                                                 \
    unsigned long long kc = (ck_);                                       \
    _Pragma("unroll")                                                    \
    for (int t = 0; t < KNN; ++t) {                                      \
        bool sw = kc < bk[t];                                            \
        unsigned long long nn = sw ? kc : bk[t];                         \
        unsigned long long oo = sw ? bk[t] : kc;                         \
        bk[t] = nn; kc = oo;                                             \
    }                                                                    \
} while (0)

#define PACKK(dv_, jv_, out_) do {                                       \
    unsigned pu = __float_as_uint(dv_);                                  \
    pu = (pu == 0x80000000u) ? 0u : pu;     /* -0 -> +0 */               \
    pu ^= (unsigned)((int)pu >> 31) | 0x80000000u;                       \
    (out_) = ((unsigned long long)pu << 32) | (unsigned)(jv_);           \
} while (0)

// Fast-path push: raw float compare vs cached threshold (superset of the exact
// key test; the chain rejects exactly at flush time).
#define PUSHF(dv_, jg_) do {                                             \
    if ((dv_) <= thr) {                                                  \
        pd3 = pd2; pj3 = pj2; pd2 = pd1; pj2 = pj1;                      \
        pd1 = pd0; pj1 = pj0; pd0 = (dv_); pj0 = (jg_); ++cnt;           \
    }                                                                    \
} while (0)

#define FLUSHF() do {                                                    \
    if (cnt > 0) { unsigned long long k0_; PACKK(pd0, pj0, k0_); KCHAIN(k0_); } \
    if (cnt > 1) { unsigned long long k1_; PACKK(pd1, pj1, k1_); KCHAIN(k1_); } \
    if (cnt > 2) { unsigned long long k2_; PACKK(pd2, pj2, k2_); KCHAIN(k2_); } \
    if (cnt > 3) { unsigned long long k3_; PACKK(pd3, pj3, k3_); KCHAIN(k3_); } \
    cnt = 0;                                                             \
    unsigned hu_ = (unsigned)(bk[KNN - 1] >> 32);                        \
    hu_ = (hu_ & 0x80000000u) ? (hu_ ^ 0x80000000u) : ~hu_;              \
    thr = __uint_as_float(hu_);                                          \
} while (0)

#define KMERGE(ptr_) do {                                                \
    const unsigned long long* mp = (ptr_);                               \
    _Pragma("unroll 1")                                                  \
    for (int tm = 0; tm < KNN; ++tm) {                                   \
        unsigned long long mk = mp[tm];                                  \
        if (mk >= bk[KNN - 1]) break;                                    \
        KCHAIN(mk);                                                      \
    }                                                                    \
} while (0)

// sentinel key = pack(+INF, 0xFFFFFFFF): greater than any finite-distance key,
// unpacks to thr=+INF (so early candidates always pass the fast-path filter).
#define KSENTINEL 0xFF800000FFFFFFFFULL

// ---------------------------------------------------------------- fused tiled kNN
// 256-thread block, 64 queries. Per 64-cand tile: [stage Cs(t) || scan Ds(t-1)]
// barrier [GEMM 4x4 micro + distance epilogue -> Ds(t)] barrier. 2 barriers/tile,
// single Ds buffer, 3 blocks/CU (LDS 49k). Scan: wave wv handles cands
// [16wv,16wv+16), lane=query; float-threshold fast path, u64-key chain at flush.
template<int C>
__global__ __launch_bounds__(256, 3) void knn_tile_kernel(const float* __restrict__ f, int ldf,
                                                          const float* __restrict__ norms,
                                                          int* __restrict__ idx) {
    const int qb    = blockIdx.x * 64;
    const int b     = qb >> 12;
    const int qloc0 = qb & (NPTS - 1);
    const int tid   = threadIdx.x;
    const int lane  = tid & 63;            // query (scan/merge role)
    const int wv    = tid >> 6;            // wave 0..3 = candidate sub-range
    const int tx    = tid & 15;            // candidate quad (GEMM role)
    const int ty    = tid >> 4;            // query quad   (GEMM role)

    union __align__(16) SM {
        struct {
            float Qs[C][64];
            float Cs[C][64];
            float Ds[64][68];              // row stride 272 B (16B-aligned)
        } a;
        unsigned long long md[64][2 * KNN + 1];
    };
    __shared__ SM sm;

    const float* fb = f + (size_t)b * NPTS * ldf;
    const float* nb = norms + (size_t)b * NPTS;

    // ---- stage query tile Qs[k][m] (once)
    if constexpr ((C & 15) == 0) {
        int m = tid >> 2, ko = (tid & 3) * 4;
        const float* src = fb + (size_t)(qloc0 + m) * ldf;
#pragma unroll
        for (int k4 = ko; k4 < C; k4 += 16) {
            float4 v = *(const float4*)(src + k4);
            sm.a.Qs[k4 + 0][m] = v.x; sm.a.Qs[k4 + 1][m] = v.y;
            sm.a.Qs[k4 + 2][m] = v.z; sm.a.Qs[k4 + 3][m] = v.w;
        }
    } else {
        for (int e = tid; e < C * 64; e += 256) {
            int k = e >> 6, m = e & 63;
            sm.a.Qs[k][m] = fb[(size_t)(qloc0 + m) * ldf + k];
        }
    }

    const float4 qnv = *(const float4*)(nb + qloc0 + ty * 4);
    const float qnr[4] = {qnv.x, qnv.y, qnv.z, qnv.w};

    unsigned long long bk[KNN];
#pragma unroll
    for (int t = 0; t < KNN; ++t) bk[t] = KSENTINEL;
    float thr = INFINITY;
    float pd0 = 0.f, pd1 = 0.f, pd2 = 0.f, pd3 = 0.f;
    int   pj0 = 0, pj1 = 0, pj2 = 0, pj3 = 0;
    int   cnt = 0;

    auto stageC = [&](int j0) {
        if constexpr ((C & 15) == 0) {
            int jj = tid >> 2, ko = (tid & 3) * 4;
            const float* src = fb + (size_t)(j0 + jj) * ldf;
#pragma unroll
            for (int k4 = ko; k4 < C; k4 += 16) {
                float4 v = *(const float4*)(src + k4);
                sm.a.Cs[k4 + 0][jj] = v.x; sm.a.Cs[k4 + 1][jj] = v.y;
                sm.a.Cs[k4 + 2][jj] = v.z; sm.a.Cs[k4 + 3][jj] = v.w;
            }
        } else {
            for (int e = tid; e < C * 64; e += 256) {
                int k = e >> 6, j = e & 63;
                sm.a.Cs[k][j] = fb[(size_t)(j0 + j) * ldf + k];
            }
        }
    };

    auto gemmT = [&](int j0) {
        float acc[4][4] = {};
#pragma unroll 8
        for (int kk = 0; kk < C; ++kk) {
            float4 av = *(const float4*)&sm.a.Qs[kk][ty * 4];
            float4 bv = *(const float4*)&sm.a.Cs[kk][tx * 4];
            float a[4] = {av.x, av.y, av.z, av.w};
            float bb[4] = {bv.x, bv.y, bv.z, bv.w};
#pragma unroll
            for (int i = 0; i < 4; ++i)
#pragma unroll
                for (int j = 0; j < 4; ++j) acc[i][j] = fmaf(a[i], bb[j], acc[i][j]);
        }
        const float4 cnv = *(const float4*)(nb + j0 + tx * 4);
#pragma unroll
        for (int i = 0; i < 4; ++i) {
            float4 o;
            o.x = fmaf(-2.0f, acc[i][0], qnr[i] + cnv.x);
            o.y = fmaf(-2.0f, acc[i][1], qnr[i] + cnv.y);
            o.z = fmaf(-2.0f, acc[i][2], qnr[i] + cnv.z);
            o.w = fmaf(-2.0f, acc[i][3], qnr[i] + cnv.w);
            *(float4*)&sm.a.Ds[ty * 4 + i][tx * 4] = o;
        }
    };

    auto scanT = [&](int j0) {
        const int jb = wv * 16;
        const float4 v0 = *(const float4*)&sm.a.Ds[lane][jb + 0];
        const float4 v1 = *(const float4*)&sm.a.Ds[lane][jb + 4];
        const float4 v2 = *(const float4*)&sm.a.Ds[lane][jb + 8];
        const float4 v3 = *(const float4*)&sm.a.Ds[lane][jb + 12];
        const int jg = j0 + jb;
        PUSHF(v0.x, jg + 0);  PUSHF(v0.y, jg + 1);  if (__any(cnt >= 3)) FLUSHF();
        PUSHF(v0.z, jg + 2);  PUSHF(v0.w, jg + 3);  if (__any(cnt >= 3)) FLUSHF();
        PUSHF(v1.x, jg + 4);  PUSHF(v1.y, jg + 5);  if (__any(cnt >= 3)) FLUSHF();
        PUSHF(v1.z, jg + 6);  PUSHF(v1.w, jg + 7);  if (__any(cnt >= 3)) FLUSHF();
        PUSHF(v2.x, jg + 8);  PUSHF(v2.y, jg + 9);  if (__any(cnt >= 3)) FLUSHF();
        PUSHF(v2.z, jg + 10); PUSHF(v2.w, jg + 11); if (__any(cnt >= 3)) FLUSHF();
        PUSHF(v3.x, jg + 12); PUSHF(v3.y, jg + 13); if (__any(cnt >= 3)) FLUSHF();
        PUSHF(v3.z, jg + 14); PUSHF(v3.w, jg + 15); if (__any(cnt >= 3)) FLUSHF();
    };

    // ---- pipelined main loop: 2 barriers per tile
    stageC(0);
    __syncthreads();
    gemmT(0);
    __syncthreads();
#pragma unroll 1
    for (int t = 1; t < NPTS / 64; ++t) {
        stageC(t * 64);          // writes Cs (gemm(t-1) done reading it)
        scanT((t - 1) * 64);     // reads Ds(t-1)
        __syncthreads();
        gemmT(t * 64);           // reads Cs(t), overwrites Ds
        __syncthreads();
    }
    scanT(NPTS - 64);
    if (__any(cnt > 0)) FLUSHF();

    // ---- hierarchical 4 -> 1 merge of sorted lists (per query = per lane)
    __syncthreads();   // all Ds reads done; alias md over a.*
    if (wv >= 2) {
#pragma unroll
        for (int t = 0; t < KNN; ++t) sm.md[lane][(wv - 2) * KNN + t] = bk[t];
    }
    __syncthreads();
    if (wv < 2) KMERGE(&sm.md[lane][wv * KNN]);
    __syncthreads();
    if (wv == 1) {
#pragma unroll
        for (int t = 0; t < KNN; ++t) sm.md[lane][t] = bk[t];
    }
    __syncthreads();
    if (wv == 0) {
        KMERGE(&sm.md[lane][0]);
        int* op = idx + (size_t)(qb + lane) * KNN;
#pragma unroll
        for (int t = 0; t < KNN; ++t) op[t] = (int)bk[t];
    }
}

// ---------------------------------------------------------------- EdgeConv (wave/point)
template<int C>
__global__ __launch_bounds__(64) void edgeconv_kernel(
    const float* __restrict__ f, int ldf,
    const int* __restrict__ idx,
    const float* __restrict__ W1, const float* __restrict__ b1,
    const float* __restrict__ g,  const float* __restrict__ be,
    const float* __restrict__ W2, const float* __restrict__ b2,
    float* __restrict__ out, int ldo) {
    const int p = blockIdx.x;
    const int b = p >> 12;
    const int i = p & (NPTS - 1);
    const int c = threadIdx.x;   // output channel, 0..63
    __shared__ __align__(16) float fi_s[C];
    __shared__ __align__(16) float fj_s[KNN][C];
    __shared__ __align__(16) float h1_s[KNN][64];
    __shared__ int nidx[KNN];
    const float* fb = f + (size_t)b * NPTS * ldf;
    if (c < KNN) nidx[c] = idx[(size_t)p * KNN + c];
    if (c < C)   fi_s[c] = fb[(size_t)i * ldf + c];
    __syncthreads();
#pragma unroll
    for (int j = 0; j < KNN; ++j)
        if (c < C) fj_s[j][c] = fb[(size_t)nidx[j] * ldf + c];
    __syncthreads();
    float fir[C];
#pragma unroll
    for (int k = 0; k < C; ++k) fir[k] = fi_s[k];

    const float bn_s = (float)(1.0 / sqrt(1.0 + 1e-5));
    const float bnscale = g[c] * bn_s;
    float base = b1[c];
#pragma unroll
    for (int k = 0; k < C; ++k) base = fmaf(fir[k], W1[k * 64 + c], base);
    float acc[KNN];
#pragma unroll
    for (int j = 0; j < KNN; ++j) acc[j] = base;

    if constexpr ((C & 3) == 0) {
#pragma unroll
        for (int k = 0; k < C; k += 4) {
            float w0 = W1[(C + k + 0) * 64 + c];
            float w1 = W1[(C + k + 1) * 64 + c];
            float w2 = W1[(C + k + 2) * 64 + c];
            float w3 = W1[(C + k + 3) * 64 + c];
            float f0 = fir[k + 0], f1 = fir[k + 1], f2 = fir[k + 2], f3 = fir[k + 3];
#pragma unroll
            for (int j = 0; j < KNN; ++j) {
                float4 v = *(const float4*)&fj_s[j][k];
                acc[j] = fmaf(v.x - f0, w0, acc[j]);
                acc[j] = fmaf(v.y - f1, w1, acc[j]);
                acc[j] = fmaf(v.z - f2, w2, acc[j]);
                acc[j] = fmaf(v.w - f3, w3, acc[j]);
            }
        }
    } else {
#pragma unroll
        for (int k = 0; k < C; ++k) {
            float w = W1[(C + k) * 64 + c];
            float fik = fir[k];
#pragma unroll
            for (int j = 0; j < KNN; ++j) acc[j] = fmaf(fj_s[j][k] - fik, w, acc[j]);
        }
    }
    float bec = be[c];
#pragma unroll
    for (int j = 0; j < KNN; ++j) h1_s[j][c] = fmaxf(fmaf(acc[j], bnscale, bec), 0.f);
    __syncthreads();

    float acc2[KNN];
    float b2c = b2[c];
#pragma unroll
    for (int j = 0; j < KNN; ++j) acc2[j] = b2c;
#pragma unroll
    for (int k = 0; k < 64; k += 4) {
        float w0 = W2[(k + 0) * 64 + c];
        float w1 = W2[(k + 1) * 64 + c];
        float w2 = W2[(k + 2) * 64 + c];
        float w3 = W2[(k + 3) * 64 + c];
#pragma unroll
        for (int j = 0; j < KNN; ++j) {
            float4 v = *(const float4*)&h1_s[j][k];
            acc2[j] = fmaf(v.x, w0, acc2[j]);
            acc2[j] = fmaf(v.y, w1, acc2[j]);
            acc2[j] = fmaf(v.z, w2, acc2[j]);
            acc2[j] = fmaf(v.w, w3, acc2[j]);
        }
    }
    float m = acc2[0];
#pragma unroll
    for (int j = 1; j < KNN; ++j) m = fmaxf(m, acc2[j]);
    out[(size_t)p * ldo + c] = m;
}

// ---------------------------------------------------------------- tiled fp32 GEMM: C = act(A@W + b)
template<int BM, int BN, int BK, bool RELU>
__global__ __launch_bounds__(256) void gemm_kernel(
    const float* __restrict__ A, int lda,
    const float* __restrict__ W,          // [K, N] row-major
    const float* __restrict__ bias,
    float* __restrict__ Cc, int ldc,
    int N, int K) {
    __shared__ __align__(16) float As[BK][BM];
    __shared__ __align__(16) float Bs[BK][BN];
    const int bm = blockIdx.y * BM;
    const int bn = blockIdx.x * BN;
    const int tid = threadIdx.x;
    const int tx = tid & 15, ty = tid >> 4;
    float acc[4][4] = {};
    for (int k0 = 0; k0 < K; k0 += BK) {
        {   // A tile: 64 rows x 16 cols, each thread float4
            int m = tid >> 2;
            int kq = (tid & 3) * 4;
            float4 v = *(const float4*)(A + (size_t)(bm + m) * lda + k0 + kq);
            As[kq + 0][m] = v.x; As[kq + 1][m] = v.y; As[kq + 2][m] = v.z; As[kq + 3][m] = v.w;
        }
        {   // W tile: 16 rows x 64 cols
            int kk = tid >> 4;
            int n4 = (tid & 15) * 4;
            float4 v = *(const float4*)(W + (size_t)(k0 + kk) * N + bn + n4);
            *(float4*)&Bs[kk][n4] = v;
        }
        __syncthreads();
#pragma unroll
        for (int kk = 0; kk < BK; ++kk) {
            float4 av = *(const float4*)&As[kk][ty * 4];
            float4 bv = *(const float4*)&Bs[kk][tx * 4];
            float a[4] = {av.x, av.y, av.z, av.w};
            float bb[4] = {bv.x, bv.y, bv.z, bv.w};
#pragma unroll
            for (int i = 0; i < 4; ++i)
#pragma unroll
                for (int j = 0; j < 4; ++j) acc[i][j] = fmaf(a[i], bb[j], acc[i][j]);
        }
        __syncthreads();
    }
#pragma unroll
    for (int i = 0; i < 4; ++i) {
        int m = bm + ty * 4 + i;
        float4 o;
        o.x = acc[i][0] + bias[bn + tx * 4 + 0];
        o.y = acc[i][1] + bias[bn + tx * 4 + 1];
        o.z = acc[i][2] + bias[bn + tx * 4 + 2];
        o.w = acc[i][3] + bias[bn + tx * 4 + 3];
        if (RELU) {
            o.x = fmaxf(o.x, 0.f); o.y = fmaxf(o.y, 0.f);
            o.z = fmaxf(o.z, 0.f); o.w = fmaxf(o.w, 0.f);
        }
        *(float4*)(Cc + (size_t)m * ldc + bn + tx * 4) = o;
    }
}

// ---------------------------------------------------------------- final layer (K=128 -> 40) + log_softmax
__global__ __launch_bounds__(64) void head_kernel(const float* __restrict__ h3,
                                                  const float* __restrict__ W4,
                                                  const float* __restrict__ b4,
                                                  float* __restrict__ out) {
    const int p = blockIdx.x;
    const int lane = threadIdx.x;
    const float* hp = h3 + (size_t)p * 128;
    float v = -INFINITY;
    if (lane < 40) {
        float acc = b4[lane];
#pragma unroll
        for (int k = 0; k < 128; ++k) acc = fmaf(hp[k], W4[k * 40 + lane], acc);
        v = acc;
    }
    float mx = v;
#pragma unroll
    for (int s = 1; s < 64; s <<= 1) mx = fmaxf(mx, __shfl_xor(mx, s));
    float e = (lane < 40) ? expf(v - mx) : 0.0f;
    float se = e;
#pragma unroll
    for (int s = 1; s < 64; s <<= 1) se += __shfl_xor(se, s);
    if (lane < 40) out[(size_t)p * 40 + lane] = v - mx - logf(se);
}

// ----------------------------------------------------------------
extern "C" void kernel_launch(void* const* d_in, const int* in_sizes, int n_in,
                              void* d_out, int out_size, void* d_ws, size_t ws_size,
                              hipStream_t stream) {
    (void)in_sizes; (void)n_in; (void)out_size; (void)ws_size;
    const float* x     = (const float*)d_in[0];
    const float* pos   = (const float*)d_in[1];
    const float* c1_W1 = (const float*)d_in[2];
    const float* c1_b1 = (const float*)d_in[3];
    const float* c1_g  = (const float*)d_in[4];
    const float* c1_be = (const float*)d_in[5];
    const float* c1_W2 = (const float*)d_in[6];
    const float* c1_b2 = (const float*)d_in[7];
    const float* c2_W1 = (const float*)d_in[8];
    const float* c2_b1 = (const float*)d_in[9];
    const float* c2_g  = (const float*)d_in[10];
    const float* c2_be = (const float*)d_in[11];
    const float* c2_W2 = (const float*)d_in[12];
    const float* c2_b2 = (const float*)d_in[13];
    const float* c3_W1 = (const float*)d_in[14];
    const float* c3_b1 = (const float*)d_in[15];
    const float* c3_g  = (const float*)d_in[16];
    const float* c3_be = (const float*)d_in[17];
    const float* c3_W2 = (const float*)d_in[18];
    const float* c3_b2 = (const float*)d_in[19];
    const float* m_W1  = (const float*)d_in[20];
    const float* m_b1  = (const float*)d_in[21];
    const float* m_W2  = (const float*)d_in[22];
    const float* m_b2  = (const float*)d_in[23];
    const float* m_W3  = (const float*)d_in[24];
    const float* m_b3  = (const float*)d_in[25];
    const float* m_W4  = (const float*)d_in[26];
    const float* m_b4  = (const float*)d_in[27];
    float* out = (float*)d_out;

    const int TOT = NB * NPTS;  // 32768

    // workspace layout (floats):
    float* ws   = (float*)d_ws;
    float* f0   = ws;                              // 196608
    int*   idxb = (int*)(ws + 196608);             // 655360 ints
    float* feat = ws + 196608 + 655360;            // 6291456  [32768 x 192]
    float* h1   = feat + 6291456;                  // 4194304  [4096 x 1024]
    float* h2   = h1 + 4194304;                    // 1048576  [4096 x 256]
    float* h3   = h2 + 1048576;                    // 524288   [4096 x 128]
    float* nrm  = h1;                              // alias: h1 only used in MLP phase

    concat_kernel<<<(TOT + 255) / 256, 256, 0, stream>>>(x, pos, f0, TOT);

    norm_kernel<6><<<(TOT + 255) / 256, 256, 0, stream>>>(f0, 6, nrm, TOT);
    knn_tile_kernel<6><<<TOT / 64, 256, 0, stream>>>(f0, 6, nrm, idxb);
    edgeconv_kernel<6><<<TOT, 64, 0, stream>>>(f0, 6, idxb,
        c1_W1, c1_b1, c1_g, c1_be, c1_W2, c1_b2, feat + 0, 192);

    norm_kernel<64><<<(TOT + 255) / 256, 256, 0, stream>>>(feat + 0, 192, nrm, TOT);
    knn_tile_kernel<64><<<TOT / 64, 256, 0, stream>>>(feat + 0, 192, nrm, idxb);
    edgeconv_kernel<64><<<TOT, 64, 0, stream>>>(feat + 0, 192, idxb,
        c2_W1, c2_b1, c2_g, c2_be, c2_W2, c2_b2, feat + 64, 192);

    norm_kernel<64><<<(TOT + 255) / 256, 256, 0, stream>>>(feat + 64, 192, nrm, TOT);
    knn_tile_kernel<64><<<TOT / 64, 256, 0, stream>>>(feat + 64, 192, nrm, idxb);
    edgeconv_kernel<64><<<TOT, 64, 0, stream>>>(feat + 64, 192, idxb,
        c3_W1, c3_b1, c3_g, c3_be, c3_W2, c3_b2, feat + 128, 192);

    const int MC = 4096;
    for (int mc = 0; mc < TOT; mc += MC) {
        gemm_kernel<64, 64, 16, true><<<dim3(1024 / 64, MC / 64), 256, 0, stream>>>(
            feat + (size_t)mc * 192, 192, m_W1, m_b1, h1, 1024, 1024, 192);
        gemm_kernel<64, 64, 16, true><<<dim3(256 / 64, MC / 64), 256, 0, stream>>>(
            h1, 1024, m_W2, m_b2, h2, 256, 256, 1024);
        gemm_kernel<64, 64, 16, true><<<dim3(128 / 64, MC / 64), 256, 0, stream>>>(
            h2, 256, m_W3, m_b3, h3, 128, 128, 256);
        head_kernel<<<MC, 64, 0, stream>>>(h3, m_W4, m_b4, out + (size_t)mc * 40);
    }
}